// Round 9
// baseline (425.649 us; speedup 1.0000x reference)
//
#include <hip/hip_runtime.h>

#define MAXB 5120      // scratch slots per bucket (mean 4096, ~16-sigma margin)
#define NBKT_MAX 512
#define TILEDGES 2048  // edges per passA block
#define ABLOCK 512     // passA threads

// Pair packing: dst in [16:0] (N < 2^17); w in (0,1) as 15-bit bf16-style
// float (8e+7m, RTN) in [31:17]. Max rel err 2^-8 ~ 0.4% — log-values err
// ~2e-3 vs 0.115 threshold.
__device__ __forceinline__ unsigned pack_pair(int dst, float w) {
  unsigned wb = __float_as_uint(w) + 0x8000u;
  return ((wb >> 16) << 17) | (unsigned)dst;
}

// Pass A v3: wave-cooperative MLP + bucket scatter.
// R8 post-mortem: LDS-staged version was latency-bound lockstep (VALUBusy
// 8%, 1.1 TB/s, occ 33%): 37.5KB LDS capped 4 blocks/CU and the per-chunk
// barrier drained vmcnt(0) 8x/block. Here: lane l of each wave reads float4
// #l of a contiguous run -> 1024B/wave-instr = 8 full rows, perfectly
// coalesced, NO LDS staging, NO barriers in the stream loop. Each 8-lane
// group owns one edge: reg-held W quad, 3 shfl_xor reduce, leader does
// softplus + the bucketed scatter (LDS cursor pre-charged with the block's
// global reservation -> scratch slot known immediately; still 1 global
// atomic per (block,bucket)).
__global__ __launch_bounds__(ABLOCK)
void passA(const float* __restrict__ feats, const float* __restrict__ W,
           const float* __restrict__ b, const int* __restrict__ src,
           const int* __restrict__ dst, float* __restrict__ out,
           float* __restrict__ er_ws, float* __restrict__ c,
           int* __restrict__ bcursor,
           unsigned long long* __restrict__ scratch, int E, int B) {
  __shared__ int lhist[NBKT_MAX];
  __shared__ int lcur[NBKT_MAX];
  int t = threadIdx.x;
  int base = blockIdx.x * TILEDGES;
  int nvalid = E - base;
  if (nvalid > TILEDGES) nvalid = TILEDGES;

  for (int k = t; k < B; k += ABLOCK) lhist[k] = 0;
  __syncthreads();
  // phase 1: block histogram of src buckets (coalesced src read, LDS atomics)
  for (int j = t; j < nvalid; j += ABLOCK)
    atomicAdd(&lhist[src[base + j] >> 8], 1);
  __syncthreads();
  // reserve global space: ONE atomic per (block,bucket); cursor = global
  // within-bucket offset so phase 2 scatters to final slots directly.
  for (int k = t; k < B; k += ABLOCK) {
    int cnt = lhist[k];
    lcur[k] = cnt ? atomicAdd(&bcursor[k], cnt) : 0;
  }
  __syncthreads();

  // phase 2: streamed wave-cooperative MLP + immediate scatter.
  const float4 wv = ((const float4*)W)[t & 7];  // this lane's 4 W coeffs
  const float bias = b[0];
  const float4* g4 = (const float4*)feats + (size_t)base * 8;
  const int totF4 = nvalid * 8;
  const int sub = t >> 3;  // 8-lane group id within block (0..63)

#pragma unroll 1
  for (int r0 = 0; r0 < TILEDGES / 64; r0 += 4) {  // 4 rounds/iter, 64 edges/round
    int j0 = r0 * ABLOCK + t;
    float4 v0, v1, v2, v3;
    v0 = (j0 + 0 * ABLOCK < totF4) ? g4[j0 + 0 * ABLOCK] : float4{0, 0, 0, 0};
    v1 = (j0 + 1 * ABLOCK < totF4) ? g4[j0 + 1 * ABLOCK] : float4{0, 0, 0, 0};
    v2 = (j0 + 2 * ABLOCK < totF4) ? g4[j0 + 2 * ABLOCK] : float4{0, 0, 0, 0};
    v3 = (j0 + 3 * ABLOCK < totF4) ? g4[j0 + 3 * ABLOCK] : float4{0, 0, 0, 0};
    float p0 = fmaf(v0.x, wv.x, fmaf(v0.y, wv.y, fmaf(v0.z, wv.z, v0.w * wv.w)));
    float p1 = fmaf(v1.x, wv.x, fmaf(v1.y, wv.y, fmaf(v1.z, wv.z, v1.w * wv.w)));
    float p2 = fmaf(v2.x, wv.x, fmaf(v2.y, wv.y, fmaf(v2.z, wv.z, v2.w * wv.w)));
    float p3 = fmaf(v3.x, wv.x, fmaf(v3.y, wv.y, fmaf(v3.z, wv.z, v3.w * wv.w)));
    p0 += __shfl_xor(p0, 1); p0 += __shfl_xor(p0, 2); p0 += __shfl_xor(p0, 4);
    p1 += __shfl_xor(p1, 1); p1 += __shfl_xor(p1, 2); p1 += __shfl_xor(p1, 4);
    p2 += __shfl_xor(p2, 1); p2 += __shfl_xor(p2, 2); p2 += __shfl_xor(p2, 4);
    p3 += __shfl_xor(p3, 1); p3 += __shfl_xor(p3, 2); p3 += __shfl_xor(p3, 4);
    if ((t & 7) == 0) {
      float pz[4] = {p0, p1, p2, p3};
#pragma unroll
      for (int i = 0; i < 4; ++i) {
        int e = base + (r0 + i) * 64 + sub;
        if (e < E) {
          float z = pz[i] + bias;
          float sp = (z > 15.0f) ? z : log1pf(expf(z));
          out[e] = -sp;
          float w = expf(-sp);
          er_ws[e] = w;  // full-precision exp(rewards) for the epilogue
          int s = src[e], d = dst[e];
          int bkt = s >> 8;
          int slot = atomicAdd(&lcur[bkt], 1);  // LDS cursor -> global slot
          scratch[(size_t)bkt * MAXB + slot] =
              ((unsigned long long)(s & 255) << 32) | pack_pair(d, w);
          // hop-1 seed: c[n] = sum_{n->0} w. ~N atomics, near-unique addrs.
          if (d == 0 && s != 0) atomicAdd(&c[s], w);
        }
      }
    }
  }
}

// Pass B: one block per bucket. Computes its own bucket base (391-int strided
// sum + LDS tree reduce), then exact within-bucket CSR entirely in LDS;
// coalesced global writes for pairs and row_ptr.
__global__ __launch_bounds__(256)
void passB(const unsigned long long* __restrict__ scratch,
           const int* __restrict__ bcursor,
           unsigned* __restrict__ pairs, int* __restrict__ row_ptr,
           int N, int B, int E) {
  __shared__ int red[256];
  __shared__ int hist[256];
  __shared__ int scan[256];
  __shared__ int cur[256];
  __shared__ unsigned lp[MAXB];
  int bkt = blockIdx.x, t = threadIdx.x;

  int part = 0;
  for (int k = t; k < bkt; k += 256) part += bcursor[k];
  red[t] = part;
  __syncthreads();
  for (int off = 128; off > 0; off >>= 1) {
    if (t < off) red[t] += red[t + off];
    __syncthreads();
  }
  int base = red[0];
  int cnt = bcursor[bkt];
  const unsigned long long* sc = scratch + (size_t)bkt * MAXB;

  hist[t] = 0;
  __syncthreads();
  for (int j = t; j < cnt; j += 256)
    atomicAdd(&hist[(int)(sc[j] >> 32) & 255], 1);
  __syncthreads();
  int v = hist[t];
  scan[t] = v;
  __syncthreads();
  for (int off = 1; off < 256; off <<= 1) {
    int u = 0;
    if (t >= off) u = scan[t - off];
    __syncthreads();
    if (t >= off) scan[t] += u;
    __syncthreads();
  }
  int ex = scan[t] - v;
  cur[t] = ex;
  int n = bkt * 256 + t;
  if (n < N) row_ptr[n] = base + ex;
  if (bkt == 0 && t == 0) row_ptr[N] = E;
  __syncthreads();
  for (int j = t; j < cnt; j += 256) {
    unsigned long long r = sc[j];
    int slot = atomicAdd(&cur[(int)(r >> 32) & 255], 1);
    lp[slot] = (unsigned)r;
  }
  __syncthreads();
  for (int j = t; j < cnt; j += 256) pairs[base + j] = lp[j];
}

// One value-iteration hop: xw[n] = c[n] + sum_row w*xr[dst]; x[0] == 0
// convention (stands for 1.0; c carries the sink contribution). 4 lanes/node,
// shfl-reduced. Relaunch per hop (~10.5us marginal). Grid barriers on gfx950
// cost ~100-200us/sync regardless of construction (agent-scope acq/rel
// forces L2 wb/inv; per-XCD L2s non-coherent) — persistent form is DEAD here.
__global__ __launch_bounds__(256)
void iter_step(const int* __restrict__ rp, const unsigned* __restrict__ pairs,
               const float* __restrict__ c, const float* __restrict__ xr,
               float* __restrict__ xw, int N) {
  int w = blockIdx.x * blockDim.x + threadIdx.x;
  int n = w >> 2;
  if (n >= N) return;
  int lane = w & 3;
  int s = rp[n];
  int epos = rp[n + 1];
  float acc = 0.0f;
  int k = s + lane;
  for (; k + 12 < epos; k += 16) {
    unsigned p0 = pairs[k];
    unsigned p1 = pairs[k + 4];
    unsigned p2 = pairs[k + 8];
    unsigned p3 = pairs[k + 12];
    float x0 = xr[p0 & 0x1FFFFu];
    float x1 = xr[p1 & 0x1FFFFu];
    float x2 = xr[p2 & 0x1FFFFu];
    float x3 = xr[p3 & 0x1FFFFu];
    acc = fmaf(__uint_as_float((p0 & 0xFFFE0000u) >> 1), x0, acc);
    acc = fmaf(__uint_as_float((p1 & 0xFFFE0000u) >> 1), x1, acc);
    acc = fmaf(__uint_as_float((p2 & 0xFFFE0000u) >> 1), x2, acc);
    acc = fmaf(__uint_as_float((p3 & 0xFFFE0000u) >> 1), x3, acc);
  }
  for (; k < epos; k += 4) {
    unsigned p = pairs[k];
    acc = fmaf(__uint_as_float((p & 0xFFFE0000u) >> 1), xr[p & 0x1FFFFu], acc);
  }
  acc += __shfl_xor(acc, 1);
  acc += __shfl_xor(acc, 2);
  if (lane == 0) xw[n] = (n == 0) ? 0.0f : (c[n] + acc);
}

__global__ void epilogue(const int* __restrict__ src, const int* __restrict__ dst,
                         const float* __restrict__ er_ws,
                         const float* __restrict__ xf,
                         float* __restrict__ out, int E, int N) {
  int t = blockIdx.x * blockDim.x + threadIdx.x;
  if (t < N) out[(size_t)E + t] = (t == 0) ? 0.0f : logf(xf[t]);
  if (t < E) {
    float er = er_ws[t];  // full-precision exp(rewards) from workspace
    int sN = src[t], dN = dst[t];
    float xs = (sN == 0) ? 1.0f : xf[sN];
    float xd = (dN == 0) ? 1.0f : xf[dN];
    out[(size_t)E + (size_t)N + t] = er * xd / xs;
  }
}

static inline size_t align16(size_t x) { return (x + 15) & ~(size_t)15; }

extern "C" void kernel_launch(void* const* d_in, const int* in_sizes, int n_in,
                              void* d_out, int out_size, void* d_ws, size_t ws_size,
                              hipStream_t stream) {
  const int E = in_sizes[0] / 2;
  const int N = in_sizes[2];
  const int* edge_index = (const int*)d_in[0];
  const float* feats = (const float*)d_in[1];  // f32 [E,32]
  const float* W = (const float*)d_in[3];      // f32 [32]
  const float* b = (const float*)d_in[4];      // f32 [1]
  const int* src = edge_index;
  const int* dst = edge_index + E;
  float* out = (float*)d_out;

  const int B = (N + 255) >> 8;  // 391 buckets for N=100000

  char* ws = (char*)d_ws;
  // ---- contiguous zero region (one memset): c | bcursor ----
  float* c = (float*)ws;    ws += align16((size_t)N * 4);  // N*4 % 16 == 0
  int* bcursor = (int*)ws;  ws += align16((size_t)NBKT_MAX * 4);
  const size_t ZBYTES = (size_t)N * 4 + (size_t)NBKT_MAX * 4;
  // ---- rest ----
  unsigned long long* scratch = (unsigned long long*)ws;
  ws += align16((size_t)B * MAXB * 8);
  unsigned* pairs = (unsigned*)ws; ws += align16((size_t)E * 4);
  float* er_ws = (float*)ws; ws += align16((size_t)E * 4);
  int* row_ptr = (int*)ws;  ws += align16((size_t)(N + 1) * 4);
  float* xA = (float*)ws;   ws += align16((size_t)N * 4);
  float* xB = (float*)ws;   ws += align16((size_t)N * 4);

  // Contraction: per-hop decay ~0.3. Truncation err at k=7 ~1.6e-2 on
  // log-values — well below the 0.115 threshold; absmax has been pinned at
  // 0.03125 through k=12 -> 10 -> 8 -> 7. Hop 1 analytic (c).
  const int iters = 7;

  hipMemsetAsync(c, 0, ZBYTES, stream);
  hipLaunchKernelGGL(passA, dim3((E + TILEDGES - 1) / TILEDGES), dim3(ABLOCK),
                     0, stream, feats, W, b, src, dst, out, er_ws, c, bcursor,
                     scratch, E, B);
  hipLaunchKernelGGL(passB, dim3(B), dim3(256), 0, stream,
                     scratch, bcursor, pairs, row_ptr, N, B, E);

  const float* xr = c;  // x1 == c (hop 1 free)
  float* xw = xA;
  const int itBlocks = (N * 4 + 255) / 256;
  for (int hop = 2; hop <= iters; ++hop) {
    hipLaunchKernelGGL(iter_step, dim3(itBlocks), dim3(256), 0, stream,
                       row_ptr, pairs, c, xr, xw, N);
    xr = xw;
    xw = (xw == xA) ? xB : xA;
  }

  hipLaunchKernelGGL(epilogue, dim3((E + 255) / 256), dim3(256), 0, stream,
                     src, dst, er_ws, xr, out, E, N);
}

// Round 10
// 415.926 us; speedup vs baseline: 1.0234x; 1.0234x over previous
//
#include <hip/hip_runtime.h>

#define MAXB 5120      // scratch slots per bucket (mean 4096, ~16-sigma margin)
#define NBKT_MAX 512
#define TILEDGES 2048  // edges per passA block
#define ABLOCK 512     // passA threads

// Pair packing: dst in [16:0] (N < 2^17); w in (0,1) as 15-bit bf16-style
// float (8e+7m, RTN) in [31:17]. Max rel err 2^-8 ~ 0.4% — log-values err
// ~2e-3 vs 0.115 threshold.
__device__ __forceinline__ unsigned pack_pair(int dst, float w) {
  unsigned wb = __float_as_uint(w) + 0x8000u;
  return ((wb >> 16) << 17) | (unsigned)dst;
}

// Pass A v4: wave-cooperative MLP with PER-THREAD EDGE OWNERSHIP.
// R9 post-mortem: v3 pinned at 128us with the whole scalar tail (softplus,
// exp, out/er_ws stores, src/dst gathers, scatter) under if((t&7)==0) —
// 8/64 lanes active, 32B leader stores, 8x wasted transcendental issue.
// v4 swizzle: group g reads its own 8 edges over 8 rounds (round r, lane q
// loads float4 64g+8r+q -> 8 full 128B lines per wave instr, fully consumed);
// 3x shfl_xor all-reduce leaves the dot in ALL lanes; lane q keeps round
// r==q. Thread t then owns edge ebase+t: the entire tail is coalesced and
// all-lane. src stashed in registers from phase 1 (same indices).
__global__ __launch_bounds__(ABLOCK)
void passA(const float* __restrict__ feats, const float* __restrict__ W,
           const float* __restrict__ b, const int* __restrict__ src,
           const int* __restrict__ dst, float* __restrict__ out,
           float* __restrict__ er_ws, float* __restrict__ c,
           int* __restrict__ bcursor,
           unsigned long long* __restrict__ scratch, int E, int B) {
  __shared__ int lhist[NBKT_MAX];
  __shared__ int lcur[NBKT_MAX];
  int t = threadIdx.x;
  int base = blockIdx.x * TILEDGES;
  int nvalid = E - base;
  if (nvalid > TILEDGES) nvalid = TILEDGES;

  for (int k = t; k < B; k += ABLOCK) lhist[k] = 0;
  __syncthreads();
  // phase 1: block histogram of src buckets; stash src values (phase 2
  // needs exactly src[base + it*512 + t] — the same elements).
  int s_reg[4];
#pragma unroll
  for (int it = 0; it < 4; ++it) {
    int j = it * ABLOCK + t;
    s_reg[it] = (j < nvalid) ? src[base + j] : -1;
    if (s_reg[it] >= 0) atomicAdd(&lhist[s_reg[it] >> 8], 1);
  }
  __syncthreads();
  // reserve global space: ONE atomic per (block,bucket); lcur = global
  // within-bucket cursor so phase 2 scatters to final slots directly.
  for (int k = t; k < B; k += ABLOCK) {
    int cnt = lhist[k];
    lcur[k] = cnt ? atomicAdd(&bcursor[k], cnt) : 0;
  }
  __syncthreads();

  // phase 2: wave-coop dot + all-lane scalar tail.
  const int g = t >> 3, q = t & 7;
  const float4 wv = ((const float4*)W)[q];  // this lane's 4 W coeffs
  const float bias = b[0];
  const float4* g4 = (const float4*)feats + (size_t)base * 8;
  const int nf4 = nvalid * 8;

#pragma unroll 1
  for (int it = 0; it < 4; ++it) {
    // 8 independent loads first (compiler keeps them in flight together)
    float4 v[8];
#pragma unroll
    for (int r = 0; r < 8; ++r) {
      int rel = it * (ABLOCK * 8) + 64 * g + 8 * r + q;
      v[r] = (rel < nf4) ? g4[rel] : float4{0, 0, 0, 0};
    }
    float z = 0.0f;
#pragma unroll
    for (int r = 0; r < 8; ++r) {
      float p = fmaf(v[r].x, wv.x,
                fmaf(v[r].y, wv.y, fmaf(v[r].z, wv.z, v[r].w * wv.w)));
      p += __shfl_xor(p, 1);
      p += __shfl_xor(p, 2);
      p += __shfl_xor(p, 4);  // all 8 lanes now hold edge (ebase + 8g + r)'s dot
      if (q == r) z = p;      // lane q keeps its own edge
    }
    int j = it * ABLOCK + t;
    if (j < nvalid) {
      int e = base + j;
      float zz = z + bias;
      float sp = (zz > 15.0f) ? zz : log1pf(expf(zz));
      out[e] = -sp;                       // coalesced full-wave store
      float w = expf(-sp);
      er_ws[e] = w;                       // coalesced full-wave store
      int s = s_reg[it];
      int d = dst[e];                     // coalesced read
      int bkt = s >> 8;
      int slot = atomicAdd(&lcur[bkt], 1);
      scratch[(size_t)bkt * MAXB + slot] =
          ((unsigned long long)(s & 255) << 32) | pack_pair(d, w);
      // hop-1 seed: c[n] = sum_{n->0} w. ~N atomics, near-unique addrs.
      if (d == 0 && s != 0) atomicAdd(&c[s], w);
    }
  }
}

// Pass B: one block per bucket. Computes its own bucket base (strided sum +
// LDS tree reduce), then exact within-bucket CSR entirely in LDS; coalesced
// global writes for pairs and row_ptr.
__global__ __launch_bounds__(256)
void passB(const unsigned long long* __restrict__ scratch,
           const int* __restrict__ bcursor,
           unsigned* __restrict__ pairs, int* __restrict__ row_ptr,
           int N, int B, int E) {
  __shared__ int red[256];
  __shared__ int hist[256];
  __shared__ int scan[256];
  __shared__ int cur[256];
  __shared__ unsigned lp[MAXB];
  int bkt = blockIdx.x, t = threadIdx.x;

  int part = 0;
  for (int k = t; k < bkt; k += 256) part += bcursor[k];
  red[t] = part;
  __syncthreads();
  for (int off = 128; off > 0; off >>= 1) {
    if (t < off) red[t] += red[t + off];
    __syncthreads();
  }
  int base = red[0];
  int cnt = bcursor[bkt];
  const unsigned long long* sc = scratch + (size_t)bkt * MAXB;

  hist[t] = 0;
  __syncthreads();
  for (int j = t; j < cnt; j += 256)
    atomicAdd(&hist[(int)(sc[j] >> 32) & 255], 1);
  __syncthreads();
  int v = hist[t];
  scan[t] = v;
  __syncthreads();
  for (int off = 1; off < 256; off <<= 1) {
    int u = 0;
    if (t >= off) u = scan[t - off];
    __syncthreads();
    if (t >= off) scan[t] += u;
    __syncthreads();
  }
  int ex = scan[t] - v;
  cur[t] = ex;
  int n = bkt * 256 + t;
  if (n < N) row_ptr[n] = base + ex;
  if (bkt == 0 && t == 0) row_ptr[N] = E;
  __syncthreads();
  for (int j = t; j < cnt; j += 256) {
    unsigned long long r = sc[j];
    int slot = atomicAdd(&cur[(int)(r >> 32) & 255], 1);
    lp[slot] = (unsigned)r;
  }
  __syncthreads();
  for (int j = t; j < cnt; j += 256) pairs[base + j] = lp[j];
}

// One value-iteration hop: xw[n] = c[n] + sum_row w*xr[dst]; x[0] == 0
// convention (stands for 1.0; c carries the sink contribution). 4 lanes/node,
// shfl-reduced. Relaunch per hop (~10.5us marginal). Grid barriers on gfx950
// cost ~100-200us/sync regardless of construction (agent-scope acq/rel
// forces L2 wb/inv; per-XCD L2s non-coherent) — persistent form is DEAD.
// writeLog: final hop also writes log(x) (fuses epilogue's N-part).
__global__ __launch_bounds__(256)
void iter_step(const int* __restrict__ rp, const unsigned* __restrict__ pairs,
               const float* __restrict__ c, const float* __restrict__ xr,
               float* __restrict__ xw, float* __restrict__ logout,
               int writeLog, int N) {
  int w = blockIdx.x * blockDim.x + threadIdx.x;
  int n = w >> 2;
  if (n >= N) return;
  int lane = w & 3;
  int s = rp[n];
  int epos = rp[n + 1];
  float acc = 0.0f;
  int k = s + lane;
  for (; k + 12 < epos; k += 16) {
    unsigned p0 = pairs[k];
    unsigned p1 = pairs[k + 4];
    unsigned p2 = pairs[k + 8];
    unsigned p3 = pairs[k + 12];
    float x0 = xr[p0 & 0x1FFFFu];
    float x1 = xr[p1 & 0x1FFFFu];
    float x2 = xr[p2 & 0x1FFFFu];
    float x3 = xr[p3 & 0x1FFFFu];
    acc = fmaf(__uint_as_float((p0 & 0xFFFE0000u) >> 1), x0, acc);
    acc = fmaf(__uint_as_float((p1 & 0xFFFE0000u) >> 1), x1, acc);
    acc = fmaf(__uint_as_float((p2 & 0xFFFE0000u) >> 1), x2, acc);
    acc = fmaf(__uint_as_float((p3 & 0xFFFE0000u) >> 1), x3, acc);
  }
  for (; k < epos; k += 4) {
    unsigned p = pairs[k];
    acc = fmaf(__uint_as_float((p & 0xFFFE0000u) >> 1), xr[p & 0x1FFFFu], acc);
  }
  acc += __shfl_xor(acc, 1);
  acc += __shfl_xor(acc, 2);
  if (lane == 0) {
    float f = (n == 0) ? 0.0f : (c[n] + acc);
    xw[n] = f;
    if (writeLog) logout[n] = (n == 0) ? 0.0f : logf(f);
  }
}

// Edge-probs only (log-values fused into the final iter_step).
__global__ void epilogue(const int* __restrict__ src, const int* __restrict__ dst,
                         const float* __restrict__ er_ws,
                         const float* __restrict__ xf,
                         float* __restrict__ out, int E, int N) {
  int t = blockIdx.x * blockDim.x + threadIdx.x;
  if (t < E) {
    float er = er_ws[t];  // full-precision exp(rewards) from workspace
    int sN = src[t], dN = dst[t];
    float xs = (sN == 0) ? 1.0f : xf[sN];
    float xd = (dN == 0) ? 1.0f : xf[dN];
    out[(size_t)E + (size_t)N + t] = er * xd / xs;
  }
}

static inline size_t align16(size_t x) { return (x + 15) & ~(size_t)15; }

extern "C" void kernel_launch(void* const* d_in, const int* in_sizes, int n_in,
                              void* d_out, int out_size, void* d_ws, size_t ws_size,
                              hipStream_t stream) {
  const int E = in_sizes[0] / 2;
  const int N = in_sizes[2];
  const int* edge_index = (const int*)d_in[0];
  const float* feats = (const float*)d_in[1];  // f32 [E,32]
  const float* W = (const float*)d_in[3];      // f32 [32]
  const float* b = (const float*)d_in[4];      // f32 [1]
  const int* src = edge_index;
  const int* dst = edge_index + E;
  float* out = (float*)d_out;

  const int B = (N + 255) >> 8;  // 391 buckets for N=100000

  char* ws = (char*)d_ws;
  // ---- contiguous zero region (one memset): c | bcursor ----
  float* c = (float*)ws;    ws += align16((size_t)N * 4);  // N*4 % 16 == 0
  int* bcursor = (int*)ws;  ws += align16((size_t)NBKT_MAX * 4);
  const size_t ZBYTES = (size_t)N * 4 + (size_t)NBKT_MAX * 4;
  // ---- rest ----
  unsigned long long* scratch = (unsigned long long*)ws;
  ws += align16((size_t)B * MAXB * 8);
  unsigned* pairs = (unsigned*)ws; ws += align16((size_t)E * 4);
  float* er_ws = (float*)ws; ws += align16((size_t)E * 4);
  int* row_ptr = (int*)ws;  ws += align16((size_t)(N + 1) * 4);
  float* xA = (float*)ws;   ws += align16((size_t)N * 4);
  float* xB = (float*)ws;   ws += align16((size_t)N * 4);

  // Contraction: per-hop decay ~0.3. Truncation err at k=7 ~1.6e-2 on
  // log-values — well below the 0.115 threshold; absmax pinned at 0.03125
  // through k=12 -> 10 -> 8 -> 7. Hop 1 analytic (c).
  const int iters = 7;

  hipMemsetAsync(c, 0, ZBYTES, stream);
  hipLaunchKernelGGL(passA, dim3((E + TILEDGES - 1) / TILEDGES), dim3(ABLOCK),
                     0, stream, feats, W, b, src, dst, out, er_ws, c, bcursor,
                     scratch, E, B);
  hipLaunchKernelGGL(passB, dim3(B), dim3(256), 0, stream,
                     scratch, bcursor, pairs, row_ptr, N, B, E);

  const float* xr = c;  // x1 == c (hop 1 free)
  float* xw = xA;
  const int itBlocks = (N * 4 + 255) / 256;
  for (int hop = 2; hop <= iters; ++hop) {
    hipLaunchKernelGGL(iter_step, dim3(itBlocks), dim3(256), 0, stream,
                       row_ptr, pairs, c, xr, xw, out + E,
                       (hop == iters) ? 1 : 0, N);
    xr = xw;
    xw = (xw == xA) ? xB : xA;
  }

  hipLaunchKernelGGL(epilogue, dim3((E + 255) / 256), dim3(256), 0, stream,
                     src, dst, er_ws, xr, out, E, N);
}

// Round 11
// 415.140 us; speedup vs baseline: 1.0253x; 1.0019x over previous
//
#include <hip/hip_runtime.h>

#define MAXB 5120      // scratch slots per bucket (mean 4096, ~16-sigma margin)
#define NBKT_MAX 512
#define TILEDGES 2048  // edges per passA block
#define ABLOCK 512     // passA threads

// Pair packing: dst in [16:0] (N < 2^17); w in (0,1) as 15-bit bf16-style
// float (8e+7m, RTN) in [31:17]. Max rel err 2^-8 ~ 0.4% — log-values err
// ~2e-3 vs 0.115 threshold.
__device__ __forceinline__ unsigned pack_pair(int dst, float w) {
  unsigned wb = __float_as_uint(w) + 0x8000u;
  return ((wb >> 16) << 17) | (unsigned)dst;
}

// Pass A v5: v4 + FORCED load batching.
// R10 post-mortem: VGPR_Count=28 proves the compiler serialized the "8
// independent loads" into load->shfl->load chains (each shfl is a ds_ op
// whose lgkmcnt gives a scheduling break) -> 32 serial HBM latencies/wave,
// ~120us across R8/R9/R10 regardless of memory layout. Fix: named regs +
// sched_barrier(0) between the load cluster and the compute cluster — all 8
// global_load_dwordx4 must issue before the first consumer wait. Last
// (partial) block takes a guarded slow path so the fast path is unpredicated.
__global__ __launch_bounds__(ABLOCK)
void passA(const float* __restrict__ feats, const float* __restrict__ W,
           const float* __restrict__ b, const int* __restrict__ src,
           const int* __restrict__ dst, float* __restrict__ out,
           float* __restrict__ er_ws, float* __restrict__ c,
           int* __restrict__ bcursor,
           unsigned long long* __restrict__ scratch, int E, int B) {
  __shared__ int lhist[NBKT_MAX];
  __shared__ int lcur[NBKT_MAX];
  int t = threadIdx.x;
  int base = blockIdx.x * TILEDGES;
  int nvalid = E - base;
  if (nvalid > TILEDGES) nvalid = TILEDGES;

  for (int k = t; k < B; k += ABLOCK) lhist[k] = 0;
  __syncthreads();
  // phase 1: block histogram of src buckets; stash src (phase 2 uses the
  // exact same elements src[base + it*512 + t]).
  int s_reg[4];
#pragma unroll
  for (int it = 0; it < 4; ++it) {
    int j = it * ABLOCK + t;
    s_reg[it] = (j < nvalid) ? src[base + j] : -1;
    if (s_reg[it] >= 0) atomicAdd(&lhist[s_reg[it] >> 8], 1);
  }
  __syncthreads();
  // reserve global space: ONE atomic per (block,bucket); lcur = global
  // within-bucket cursor so phase 2 scatters to final slots directly.
  for (int k = t; k < B; k += ABLOCK) {
    int cnt = lhist[k];
    lcur[k] = cnt ? atomicAdd(&bcursor[k], cnt) : 0;
  }
  __syncthreads();

  // phase 2: wave-coop dot (coalesced: wave covers 8 full 128B lines per
  // round-instr) + all-lane coalesced scalar tail (v4's ownership swizzle).
  const int g = t >> 3, q = t & 7;
  const float4 wv = ((const float4*)W)[q];
  const float bias = b[0];
  const float4* g4 = (const float4*)feats + (size_t)base * 8;
  const int nf4 = nvalid * 8;
  const bool full = (nvalid == TILEDGES);  // block-uniform

#pragma unroll 1
  for (int it = 0; it < 4; ++it) {
    float4 v0, v1, v2, v3, v4, v5, v6, v7;
    int rel = it * (ABLOCK * 8) + 64 * g + q;
    if (full) {
      // unpredicated 8-deep load cluster
      v0 = g4[rel + 0];
      v1 = g4[rel + 8];
      v2 = g4[rel + 16];
      v3 = g4[rel + 24];
      v4 = g4[rel + 32];
      v5 = g4[rel + 40];
      v6 = g4[rel + 48];
      v7 = g4[rel + 56];
    } else {
      const float4 zz4{0, 0, 0, 0};
      v0 = (rel + 0 < nf4) ? g4[rel + 0] : zz4;
      v1 = (rel + 8 < nf4) ? g4[rel + 8] : zz4;
      v2 = (rel + 16 < nf4) ? g4[rel + 16] : zz4;
      v3 = (rel + 24 < nf4) ? g4[rel + 24] : zz4;
      v4 = (rel + 32 < nf4) ? g4[rel + 32] : zz4;
      v5 = (rel + 40 < nf4) ? g4[rel + 40] : zz4;
      v6 = (rel + 48 < nf4) ? g4[rel + 48] : zz4;
      v7 = (rel + 56 < nf4) ? g4[rel + 56] : zz4;
    }
    // fence: nothing crosses — all 8 loads issue before any consumer wait.
    __builtin_amdgcn_sched_barrier(0);
    float z = 0.0f;
    float4 vv[8] = {v0, v1, v2, v3, v4, v5, v6, v7};
#pragma unroll
    for (int r = 0; r < 8; ++r) {
      float p = fmaf(vv[r].x, wv.x,
                fmaf(vv[r].y, wv.y, fmaf(vv[r].z, wv.z, vv[r].w * wv.w)));
      p += __shfl_xor(p, 1);
      p += __shfl_xor(p, 2);
      p += __shfl_xor(p, 4);  // all 8 lanes hold edge (base+it*512+64g+r)'s dot
      if (q == r) z = p;      // lane q keeps its own edge
    }
    int j = it * ABLOCK + t;
    if (j < nvalid) {
      int e = base + j;
      float zf = z + bias;
      float sp = (zf > 15.0f) ? zf : log1pf(expf(zf));
      out[e] = -sp;                       // coalesced full-wave store
      float w = expf(-sp);
      er_ws[e] = w;                       // coalesced full-wave store
      int s = s_reg[it];
      int d = dst[e];                     // coalesced read
      int bkt = s >> 8;
      int slot = atomicAdd(&lcur[bkt], 1);
      scratch[(size_t)bkt * MAXB + slot] =
          ((unsigned long long)(s & 255) << 32) | pack_pair(d, w);
      // hop-1 seed: c[n] = sum_{n->0} w. ~N atomics, near-unique addrs.
      if (d == 0 && s != 0) atomicAdd(&c[s], w);
    }
  }
}

// Pass B: one block per bucket. Computes its own bucket base (strided sum +
// LDS tree reduce), then exact within-bucket CSR entirely in LDS; coalesced
// global writes for pairs and row_ptr.
__global__ __launch_bounds__(256)
void passB(const unsigned long long* __restrict__ scratch,
           const int* __restrict__ bcursor,
           unsigned* __restrict__ pairs, int* __restrict__ row_ptr,
           int N, int B, int E) {
  __shared__ int red[256];
  __shared__ int hist[256];
  __shared__ int scan[256];
  __shared__ int cur[256];
  __shared__ unsigned lp[MAXB];
  int bkt = blockIdx.x, t = threadIdx.x;

  int part = 0;
  for (int k = t; k < bkt; k += 256) part += bcursor[k];
  red[t] = part;
  __syncthreads();
  for (int off = 128; off > 0; off >>= 1) {
    if (t < off) red[t] += red[t + off];
    __syncthreads();
  }
  int base = red[0];
  int cnt = bcursor[bkt];
  const unsigned long long* sc = scratch + (size_t)bkt * MAXB;

  hist[t] = 0;
  __syncthreads();
  for (int j = t; j < cnt; j += 256)
    atomicAdd(&hist[(int)(sc[j] >> 32) & 255], 1);
  __syncthreads();
  int v = hist[t];
  scan[t] = v;
  __syncthreads();
  for (int off = 1; off < 256; off <<= 1) {
    int u = 0;
    if (t >= off) u = scan[t - off];
    __syncthreads();
    if (t >= off) scan[t] += u;
    __syncthreads();
  }
  int ex = scan[t] - v;
  cur[t] = ex;
  int n = bkt * 256 + t;
  if (n < N) row_ptr[n] = base + ex;
  if (bkt == 0 && t == 0) row_ptr[N] = E;
  __syncthreads();
  for (int j = t; j < cnt; j += 256) {
    unsigned long long r = sc[j];
    int slot = atomicAdd(&cur[(int)(r >> 32) & 255], 1);
    lp[slot] = (unsigned)r;
  }
  __syncthreads();
  for (int j = t; j < cnt; j += 256) pairs[base + j] = lp[j];
}

// One value-iteration hop: xw[n] = c[n] + sum_row w*xr[dst]; x[0] == 0
// convention (stands for 1.0; c carries the sink contribution). 4 lanes/node,
// shfl-reduced. Relaunch per hop (~10.5us marginal). Grid barriers on gfx950
// cost ~100-200us/sync regardless of construction (agent-scope acq/rel
// forces L2 wb/inv; per-XCD L2s non-coherent) — persistent form is DEAD.
// writeLog: final hop also writes log(x) (fuses epilogue's N-part).
__global__ __launch_bounds__(256)
void iter_step(const int* __restrict__ rp, const unsigned* __restrict__ pairs,
               const float* __restrict__ c, const float* __restrict__ xr,
               float* __restrict__ xw, float* __restrict__ logout,
               int writeLog, int N) {
  int w = blockIdx.x * blockDim.x + threadIdx.x;
  int n = w >> 2;
  if (n >= N) return;
  int lane = w & 3;
  int s = rp[n];
  int epos = rp[n + 1];
  float acc = 0.0f;
  int k = s + lane;
  for (; k + 12 < epos; k += 16) {
    unsigned p0 = pairs[k];
    unsigned p1 = pairs[k + 4];
    unsigned p2 = pairs[k + 8];
    unsigned p3 = pairs[k + 12];
    float x0 = xr[p0 & 0x1FFFFu];
    float x1 = xr[p1 & 0x1FFFFu];
    float x2 = xr[p2 & 0x1FFFFu];
    float x3 = xr[p3 & 0x1FFFFu];
    acc = fmaf(__uint_as_float((p0 & 0xFFFE0000u) >> 1), x0, acc);
    acc = fmaf(__uint_as_float((p1 & 0xFFFE0000u) >> 1), x1, acc);
    acc = fmaf(__uint_as_float((p2 & 0xFFFE0000u) >> 1), x2, acc);
    acc = fmaf(__uint_as_float((p3 & 0xFFFE0000u) >> 1), x3, acc);
  }
  for (; k < epos; k += 4) {
    unsigned p = pairs[k];
    acc = fmaf(__uint_as_float((p & 0xFFFE0000u) >> 1), xr[p & 0x1FFFFu], acc);
  }
  acc += __shfl_xor(acc, 1);
  acc += __shfl_xor(acc, 2);
  if (lane == 0) {
    float f = (n == 0) ? 0.0f : (c[n] + acc);
    xw[n] = f;
    if (writeLog) logout[n] = (n == 0) ? 0.0f : logf(f);
  }
}

// Edge-probs only (log-values fused into the final iter_step).
__global__ void epilogue(const int* __restrict__ src, const int* __restrict__ dst,
                         const float* __restrict__ er_ws,
                         const float* __restrict__ xf,
                         float* __restrict__ out, int E, int N) {
  int t = blockIdx.x * blockDim.x + threadIdx.x;
  if (t < E) {
    float er = er_ws[t];  // full-precision exp(rewards) from workspace
    int sN = src[t], dN = dst[t];
    float xs = (sN == 0) ? 1.0f : xf[sN];
    float xd = (dN == 0) ? 1.0f : xf[dN];
    out[(size_t)E + (size_t)N + t] = er * xd / xs;
  }
}

static inline size_t align16(size_t x) { return (x + 15) & ~(size_t)15; }

extern "C" void kernel_launch(void* const* d_in, const int* in_sizes, int n_in,
                              void* d_out, int out_size, void* d_ws, size_t ws_size,
                              hipStream_t stream) {
  const int E = in_sizes[0] / 2;
  const int N = in_sizes[2];
  const int* edge_index = (const int*)d_in[0];
  const float* feats = (const float*)d_in[1];  // f32 [E,32]
  const float* W = (const float*)d_in[3];      // f32 [32]
  const float* b = (const float*)d_in[4];      // f32 [1]
  const int* src = edge_index;
  const int* dst = edge_index + E;
  float* out = (float*)d_out;

  const int B = (N + 255) >> 8;  // 391 buckets for N=100000

  char* ws = (char*)d_ws;
  // ---- contiguous zero region (one memset): c | bcursor ----
  float* c = (float*)ws;    ws += align16((size_t)N * 4);  // N*4 % 16 == 0
  int* bcursor = (int*)ws;  ws += align16((size_t)NBKT_MAX * 4);
  const size_t ZBYTES = (size_t)N * 4 + (size_t)NBKT_MAX * 4;
  // ---- rest ----
  unsigned long long* scratch = (unsigned long long*)ws;
  ws += align16((size_t)B * MAXB * 8);
  unsigned* pairs = (unsigned*)ws; ws += align16((size_t)E * 4);
  float* er_ws = (float*)ws; ws += align16((size_t)E * 4);
  int* row_ptr = (int*)ws;  ws += align16((size_t)(N + 1) * 4);
  float* xA = (float*)ws;   ws += align16((size_t)N * 4);
  float* xB = (float*)ws;   ws += align16((size_t)N * 4);

  // Contraction: per-hop decay ~0.3. Truncation err at k=7 ~1.6e-2 on
  // log-values — well below the 0.115 threshold; absmax pinned at 0.03125
  // through k=12 -> 10 -> 8 -> 7. Hop 1 analytic (c).
  const int iters = 7;

  hipMemsetAsync(c, 0, ZBYTES, stream);
  hipLaunchKernelGGL(passA, dim3((E + TILEDGES - 1) / TILEDGES), dim3(ABLOCK),
                     0, stream, feats, W, b, src, dst, out, er_ws, c, bcursor,
                     scratch, E, B);
  hipLaunchKernelGGL(passB, dim3(B), dim3(256), 0, stream,
                     scratch, bcursor, pairs, row_ptr, N, B, E);

  const float* xr = c;  // x1 == c (hop 1 free)
  float* xw = xA;
  const int itBlocks = (N * 4 + 255) / 256;
  for (int hop = 2; hop <= iters; ++hop) {
    hipLaunchKernelGGL(iter_step, dim3(itBlocks), dim3(256), 0, stream,
                       row_ptr, pairs, c, xr, xw, out + E,
                       (hop == iters) ? 1 : 0, N);
    xr = xw;
    xw = (xw == xA) ? xB : xA;
  }

  hipLaunchKernelGGL(epilogue, dim3((E + 255) / 256), dim3(256), 0, stream,
                     src, dst, er_ws, xr, out, E, N);
}